// Round 22
// baseline (122.850 us; speedup 1.0000x reference)
//
#include <hip/hip_runtime.h>

typedef __bf16 bf16x8 __attribute__((ext_vector_type(8)));
typedef float f32x4 __attribute__((ext_vector_type(4)));
typedef float f32x16 __attribute__((ext_vector_type(16)));

__device__ __forceinline__ unsigned short f2bf(float f) {
    unsigned u = __builtin_bit_cast(unsigned, f);
    u += 0x7FFFu + ((u >> 16) & 1u);   // RNE
    return (unsigned short)(u >> 16);
}
__device__ __forceinline__ float bf2f(unsigned short u) {
    return __builtin_bit_cast(float, (unsigned)u << 16);
}
__device__ __forceinline__ unsigned cvtpk_bf16(float lo, float hi) {
    unsigned r;
    asm("v_cvt_pk_bf16_f32 %0, %1, %2" : "=v"(r) : "v"(lo), "v"(hi));
    return r;
}
__device__ __forceinline__ float exp2_hw(float x) {
    float r;
    asm("v_exp_f32 %0, %1" : "=v"(r) : "v"(x));
    return r;
}

// async global->LDS, 16B per lane; LDS dest = wave-uniform base + lane*16
__device__ __forceinline__ void gload16(const void* g, void* l) {
    __builtin_amdgcn_global_load_lds(
        (const __attribute__((address_space(1))) void*)g,
        (__attribute__((address_space(3))) void*)l, 16, 0, 0);
}

// ---------------- fp32 -> bf16 conversion: x + all 4 weights, one launch ----------------
__global__ __launch_bounds__(256) void cvt_all(const float* __restrict__ x,
    const float* __restrict__ w0, const float* __restrict__ w1,
    const float* __restrict__ w2, const float* __restrict__ w3,
    unsigned short* __restrict__ xb, unsigned short* __restrict__ wout)
{
    int i = blockIdx.x * 256 + threadIdx.x;
    const float* src;
    unsigned short* dst;
    int j;
    if (i < 1048576) {
        src = x; dst = xb; j = i;
    } else {
        int k = i - 1048576;
        int m = k >> 18;
        src = (m == 0) ? w0 : (m == 1) ? w1 : (m == 2) ? w2 : w3;
        dst = wout + (size_t)m * 1048576;
        j = k & 262143;
    }
    float4 v = reinterpret_cast<const float4*>(src)[j];
    ushort4 o;
    o.x = f2bf(v.x); o.y = f2bf(v.y); o.z = f2bf(v.z); o.w = f2bf(v.w);
    reinterpret_cast<ushort4*>(dst)[j] = o;
}

// ---------------- fused QKV projection: BM=128 x BN=64 ----------------
// grid 1536 = 8 XCDs x (16m x 12n); each 64-col tile lies wholly in Q, K, or V.
__global__ __launch_bounds__(256) void qkv_gemm(const unsigned short* __restrict__ X,
    const unsigned short* __restrict__ Wqkv,
    const float* __restrict__ bq, const float* __restrict__ bk, const float* __restrict__ bv,
    unsigned short* __restrict__ Qb, unsigned short* __restrict__ Kb, unsigned short* __restrict__ Vt)
{
    __shared__ __align__(16) unsigned short sA[128 * 64];   // 16 KB
    __shared__ __align__(16) unsigned short sW[64 * 64];    // 8 KB
    f32x4 acc[4][2] = {};
    const int id = blockIdx.x;
    const int xcd = id & 7, local = id >> 3;        // 1536 = 8 x 192
    const int m = (xcd & 1) * 16 + (local & 15);    // 2 m-chunks of 16
    const int n = (xcd >> 1) * 12 + (local >> 4);   // 4 n-chunks of 12
    const int m0 = m * 128, n0 = n * 64;

    const int tid  = threadIdx.x;
    const int lane = tid & 63;
    const int wv   = tid >> 6;
    const int wm   = wv >> 1, wn = wv & 1;   // 2x2 wave grid, 64x32 per wave
    const int lrow = lane >> 3;
    const int lchunk = (lane & 7) ^ lrow;

    char* sAc = reinterpret_cast<char*>(sA);
    char* sWc = reinterpret_cast<char*>(sW);

    for (int kt = 0; kt < 1024; kt += 64) {
        __syncthreads();
        #pragma unroll
        for (int j = 0; j < 4; ++j) {
            int row = (wv * 4 + j) * 8 + lrow;   // 0..127
            gload16(X + (size_t)(m0 + row) * 1024 + kt + lchunk * 8, sAc + (wv * 4 + j) * 1024);
        }
        #pragma unroll
        for (int j = 0; j < 2; ++j) {
            int row = (wv * 2 + j) * 8 + lrow;   // 0..63
            gload16(Wqkv + (size_t)(n0 + row) * 1024 + kt + lchunk * 8, sWc + (wv * 2 + j) * 1024);
        }
        __syncthreads();
        #pragma unroll
        for (int kk = 0; kk < 2; ++kk) {
            bf16x8 af[4], wf[2];
            #pragma unroll
            for (int r = 0; r < 4; ++r) {
                int rowA = wm * 64 + r * 16 + (lane & 15);
                int ca = ((kk * 4 + (lane >> 4)) ^ (rowA & 7)) * 16;
                af[r] = *reinterpret_cast<const bf16x8*>(sAc + rowA * 128 + ca);
            }
            #pragma unroll
            for (int c = 0; c < 2; ++c) {
                int rowW = wn * 32 + c * 16 + (lane & 15);
                int cw = ((kk * 4 + (lane >> 4)) ^ (rowW & 7)) * 16;
                wf[c] = *reinterpret_cast<const bf16x8*>(sWc + rowW * 128 + cw);
            }
            #pragma unroll
            for (int r = 0; r < 4; ++r)
                #pragma unroll
                for (int c = 0; c < 2; ++c)
                    acc[r][c] = __builtin_amdgcn_mfma_f32_16x16x32_bf16(af[r], wf[c], acc[r][c], 0, 0, 0);
        }
    }

    const int mid = n0 >> 10;                 // 0=Q 1=K 2=V
    const float* bias = (mid == 0) ? bq : (mid == 1) ? bk : bv;
    const float qs = (mid == 0) ? 0.18033688011112042f : 1.0f;   // 0.125*log2(e)
    #pragma unroll
    for (int r = 0; r < 4; ++r) {
        #pragma unroll
        for (int c = 0; c < 2; ++c) {
            int colg = n0 + wn * 32 + c * 16 + (lane & 15);
            int col = colg & 1023;
            float bb = bias[col];
            int row0 = m0 + wm * 64 + r * 16 + 4 * (lane >> 4);
            if (mid == 2) {
                ushort4 sv;
                sv.x = f2bf(acc[r][c][0] + bb);
                sv.y = f2bf(acc[r][c][1] + bb);
                sv.z = f2bf(acc[r][c][2] + bb);
                sv.w = f2bf(acc[r][c][3] + bb);
                *reinterpret_cast<ushort4*>(
                    Vt + ((size_t)((row0 >> 11) * 1024 + col)) * 2048 + (row0 & 2047)) = sv;
            } else {
                #pragma unroll
                for (int e = 0; e < 4; ++e) {
                    unsigned short bf = f2bf((acc[r][c][e] + bb) * qs);
                    if (mid == 0) Qb[(size_t)(row0 + e) * 1024 + col] = bf;
                    else          Kb[(size_t)(row0 + e) * 1024 + col] = bf;
                }
            }
        }
    }
}

// ---------------- output projection: BM=128 x BN=64 tiles, grid (32,16) ----------------
__global__ __launch_bounds__(256) void out_gemm(const unsigned short* __restrict__ O,
    const unsigned short* __restrict__ Wo, const float* __restrict__ bo,
    float* __restrict__ out)
{
    __shared__ __align__(16) unsigned short sA[128 * 64];   // 16 KB
    __shared__ __align__(16) unsigned short sW[64 * 64];    // 8 KB
    f32x4 acc[4][2] = {};
    const int m0 = blockIdx.x * 128, n0 = blockIdx.y * 64;

    const int tid  = threadIdx.x;
    const int lane = tid & 63;
    const int wv   = tid >> 6;
    const int wm   = wv >> 1, wn = wv & 1;   // 2x2 wave grid, 64x32 per wave
    const int lrow = lane >> 3;
    const int lchunk = (lane & 7) ^ lrow;

    char* sAc = reinterpret_cast<char*>(sA);
    char* sWc = reinterpret_cast<char*>(sW);

    for (int kt = 0; kt < 1024; kt += 64) {
        __syncthreads();
        #pragma unroll
        for (int j = 0; j < 4; ++j) {
            int row = (wv * 4 + j) * 8 + lrow;   // 0..127
            gload16(O + (size_t)(m0 + row) * 1024 + kt + lchunk * 8, sAc + (wv * 4 + j) * 1024);
        }
        #pragma unroll
        for (int j = 0; j < 2; ++j) {
            int row = (wv * 2 + j) * 8 + lrow;   // 0..63
            gload16(Wo + (size_t)(n0 + row) * 1024 + kt + lchunk * 8, sWc + (wv * 2 + j) * 1024);
        }
        __syncthreads();
        #pragma unroll
        for (int kk = 0; kk < 2; ++kk) {
            bf16x8 af[4], wf[2];
            #pragma unroll
            for (int r = 0; r < 4; ++r) {
                int rowA = wm * 64 + r * 16 + (lane & 15);
                int ca = ((kk * 4 + (lane >> 4)) ^ (rowA & 7)) * 16;
                af[r] = *reinterpret_cast<const bf16x8*>(sAc + rowA * 128 + ca);
            }
            #pragma unroll
            for (int c = 0; c < 2; ++c) {
                int rowW = wn * 32 + c * 16 + (lane & 15);
                int cw = ((kk * 4 + (lane >> 4)) ^ (rowW & 7)) * 16;
                wf[c] = *reinterpret_cast<const bf16x8*>(sWc + rowW * 128 + cw);
            }
            #pragma unroll
            for (int r = 0; r < 4; ++r)
                #pragma unroll
                for (int c = 0; c < 2; ++c)
                    acc[r][c] = __builtin_amdgcn_mfma_f32_16x16x32_bf16(af[r], wf[c], acc[r][c], 0, 0, 0);
        }
    }

    #pragma unroll
    for (int r = 0; r < 4; ++r) {
        #pragma unroll
        for (int c = 0; c < 2; ++c) {
            int col = n0 + wn * 32 + c * 16 + (lane & 15);
            float bb = bo[col];
            #pragma unroll
            for (int e = 0; e < 4; ++e) {
                int row = m0 + wm * 64 + r * 16 + 4 * (lane >> 4) + e;
                out[(size_t)row * 1024 + col] = acc[r][c][e] + bb;
            }
        }
    }
}

// ---------------- merge the two kv-halves (linear weights, shared zero shift) ----------------
__global__ __launch_bounds__(256) void combine_kernel(
    const unsigned short* __restrict__ O0, const unsigned short* __restrict__ O1,
    const float* __restrict__ lbase, unsigned short* __restrict__ Ob)
{
    int idx = blockIdx.x * 256 + threadIdx.x;
    int row = idx >> 7;              // 128 uint4 per row of 1024
    int h = (idx & 127) >> 3;        // 8 uint4 per head
    float lsum = lbase[row * 16 + h] + lbase[65536 + row * 16 + h];
    float inv = 1.0f / lsum;
    uint4 x0 = reinterpret_cast<const uint4*>(O0)[idx];
    uint4 x1 = reinterpret_cast<const uint4*>(O1)[idx];
    const unsigned* p0 = reinterpret_cast<const unsigned*>(&x0);
    const unsigned* p1 = reinterpret_cast<const unsigned*>(&x1);
    uint4 o;
    unsigned* po = reinterpret_cast<unsigned*>(&o);
    #pragma unroll
    for (int wd = 0; wd < 4; ++wd) {
        float lo = bf2f((unsigned short)(p0[wd] & 0xFFFF)) + bf2f((unsigned short)(p1[wd] & 0xFFFF));
        float hi = bf2f((unsigned short)(p0[wd] >> 16)) + bf2f((unsigned short)(p1[wd] >> 16));
        po[wd] = cvtpk_bf16(lo * inv, hi * inv);
    }
    reinterpret_cast<uint4*>(Ob)[idx] = o;
}

// ---------------- flash attention, kv-split x2, T15 software pipeline ----------------
// grid 512 x 512thr, XCD-swizzled. Per iter t: QK^T(t+1) [MFMA] issues BEFORE
// softmax(t) [VALU] so the pipes overlap; PV(t) follows. Two P-states ping-ponged
// via 2x-unrolled loop (all pP indices compile-time). Buffers: sK/sV x2; at iter t
// reads sK[(t+1)&1], sV[t&1]; writes sK[t&1] (K t+2), sV[(t+1)&1] (V t+1) - disjoint.
__global__ __launch_bounds__(512) void attn_kernel(const unsigned short* __restrict__ Qb,
    const unsigned short* __restrict__ Kb, const unsigned short* __restrict__ Vt,
    unsigned short* __restrict__ Oq0, unsigned short* __restrict__ Oq1,
    float* __restrict__ lbase)
{
    __shared__ __align__(16) unsigned short sK[2][64 * 64];   // [buf][kv][d]
    __shared__ __align__(16) unsigned short sV[2][64 * 64];   // [buf][d][kv]

    const int id = blockIdx.x;
    const int swz = (id & 7) * 64 + (id >> 3);          // bijective (512%8==0)
    const int qt = swz & 7;                             // 8 q-tiles of 256 rows
    const int bh = (swz >> 3) & 31;
    const int half = swz >> 8;                          // 0 or 1
    const int b = bh >> 4, h = bh & 15;
    const int tid = threadIdx.x, lane = tid & 63, wv = tid >> 6;   // wv 0..7
    const int qq = lane & 31, hi = lane >> 5;

    unsigned short* Oh = half ? Oq1 : Oq0;
    float* lq = lbase + half * 65536;

    const int qrow0 = b * 2048 + qt * 256 + wv * 32;
    const int kv0 = half * 1024;

    bf16x8 qf[4];
    #pragma unroll
    for (int ks = 0; ks < 4; ++ks)
        qf[ks] = *reinterpret_cast<const bf16x8*>(
            Qb + (size_t)(qrow0 + qq) * 1024 + h * 64 + ks * 16 + hi * 8);

    f32x16 oacc[2] = {};           // U^T: rows d, col q=qq (unnormalized)
    f32x16 pP[2][2];               // two P-states (ping-pong), [state][mt]
    float l_sum = 0.f;

    const unsigned short* Kbase = Kb + (size_t)b * 2048 * 1024 + h * 64;
    const unsigned short* Vbase = Vt + (size_t)(bh * 64) * 2048;

    const int lrow = lane >> 3;              // 0..7
    const int lchunk = (lane & 7) ^ lrow;    // pre-swizzled source chunk

    char* sKbase = reinterpret_cast<char*>(sK);
    char* sVbase = reinterpret_cast<char*>(sV);

    #define FILL_K(buf, kvoff)                                                           \
        {                                                                                \
            int row = wv * 8 + lrow;                                                     \
            gload16(Kbase + (size_t)((kvoff) + row) * 1024 + lchunk * 8,                 \
                    sKbase + (buf) * 8192 + wv * 1024);                                  \
        }
    #define FILL_V(buf, kvoff)                                                           \
        {                                                                                \
            int row = wv * 8 + lrow;                                                     \
            gload16(Vbase + (size_t)row * 2048 + (kvoff) + lchunk * 8,                   \
                    sVbase + (buf) * 8192 + wv * 1024);                                  \
        }

    // QK^T of tile tn into state S (reads sK[tn&1])
    #define QKT(S, tn)                                                                   \
        {                                                                                \
            const char* bK = sKbase + ((tn) & 1) * 8192;                                 \
            __builtin_amdgcn_s_setprio(1);                                               \
            _Pragma("unroll")                                                            \
            for (int mt = 0; mt < 2; ++mt) {                                             \
                f32x16 acc = {};                                                         \
                int row = mt * 32 + qq;                                                  \
                _Pragma("unroll")                                                        \
                for (int ks = 0; ks < 4; ++ks) {                                         \
                    int c = ((ks * 2 + hi) ^ (row & 7)) * 16;                            \
                    bf16x8 kf = *reinterpret_cast<const bf16x8*>(bK + row * 128 + c);    \
                    acc = __builtin_amdgcn_mfma_f32_32x32x16_bf16(kf, qf[ks], acc, 0, 0, 0); \
                }                                                                        \
                pP[S][mt] = acc;                                                         \
            }                                                                            \
            __builtin_amdgcn_s_setprio(0);                                               \
        }

    // softmax + PV of tile t using state S (reads sV[t&1])
    #define SMPV(S, t)                                                                   \
        {                                                                                \
            float rs0 = 0.f, rs1 = 0.f, rs2 = 0.f, rs3 = 0.f;                            \
            _Pragma("unroll")                                                            \
            for (int mt = 0; mt < 2; ++mt) {                                             \
                _Pragma("unroll")                                                        \
                for (int r = 0; r < 16; r += 4) {                                        \
                    float p0 = exp2_hw(pP[S][mt][r + 0]);                                \
                    float p1 = exp2_hw(pP[S][mt][r + 1]);                                \
                    float p2 = exp2_hw(pP[S][mt][r + 2]);                                \
                    float p3 = exp2_hw(pP[S][mt][r + 3]);                                \
                    pP[S][mt][r + 0] = p0; rs0 += p0;                                    \
                    pP[S][mt][r + 1] = p1; rs1 += p1;                                    \
                    pP[S][mt][r + 2] = p2; rs2 += p2;                                    \
                    pP[S][mt][r + 3] = p3; rs3 += p3;                                    \
                }                                                                        \
            }                                                                            \
            l_sum += (rs0 + rs1) + (rs2 + rs3);                                          \
            const char* bV = sVbase + ((t) & 1) * 8192;                                  \
            __builtin_amdgcn_s_setprio(1);                                               \
            _Pragma("unroll")                                                            \
            for (int mt = 0; mt < 2; ++mt) {                                             \
                _Pragma("unroll")                                                        \
                for (int halfk = 0; halfk < 2; ++halfk) {                                \
                    int r0 = halfk * 8;                                                  \
                    unsigned A0 = cvtpk_bf16(pP[S][mt][r0 + 0], pP[S][mt][r0 + 1]);      \
                    unsigned A1 = cvtpk_bf16(pP[S][mt][r0 + 2], pP[S][mt][r0 + 3]);      \
                    unsigned B0 = cvtpk_bf16(pP[S][mt][r0 + 4], pP[S][mt][r0 + 5]);      \
                    unsigned B1 = cvtpk_bf16(pP[S][mt][r0 + 6], pP[S][mt][r0 + 7]);      \
                    unsigned t0 = hi ? A0 : B0;                                          \
                    unsigned t1 = hi ? A1 : B1;                                          \
                    unsigned r0x = (unsigned)__shfl_xor((int)t0, 32);                    \
                    unsigned r1x = (unsigned)__shfl_xor((int)t1, 32);                    \
                    union { unsigned u[4]; bf16x8 v; } pf;                               \
                    pf.u[0] = hi ? r0x : A0;                                             \
                    pf.u[1] = hi ? r1x : A1;                                             \
                    pf.u[2] = hi ? B0 : r0x;                                             \
                    pf.u[3] = hi ? B1 : r1x;                                             \
                    int ks = mt * 2 + halfk;                                             \
                    _Pragma("unroll")                                                    \
                    for (int dt = 0; dt < 2; ++dt) {                                     \
                        int row = dt * 32 + qq;                                          \
                        int c = ((ks * 2 + hi) ^ (row & 7)) * 16;                        \
                        bf16x8 vf = *reinterpret_cast<const bf16x8*>(bV + row * 128 + c);\
                        oacc[dt] = __builtin_amdgcn_mfma_f32_32x32x16_bf16(vf, pf.v, oacc[dt], 0, 0, 0); \
                    }                                                                    \
                }                                                                        \
            }                                                                            \
            __builtin_amdgcn_s_setprio(0);                                               \
        }

    // prologue: stage tile0; QKT(0); stage K1
    FILL_K(0, kv0)
    FILL_V(0, kv0)
    __syncthreads();
    FILL_K(1, kv0 + 64)
    QKT(0, 0)
    __syncthreads();   // K1 staged

    // main loop, 16 tiles, 2x unrolled for ping-pong (states 0/1)
    for (int tt = 0; tt < 16; tt += 2) {
        // --- iter t = tt (state cur=0, nxt=1) ---
        if (tt < 14) FILL_K(tt & 1, kv0 + (tt + 2) * 64)
        if (tt < 15) {
            FILL_V((tt + 1) & 1, kv0 + (tt + 1) * 64)
            QKT(1, tt + 1)
        }
        SMPV(0, tt)
        __syncthreads();
        // --- iter t = tt+1 (state cur=1, nxt=0) ---
        {
            const int t1 = tt + 1;
            if (t1 < 14) FILL_K(t1 & 1, kv0 + (t1 + 2) * 64)
            if (t1 < 15) {
                FILL_V((t1 + 1) & 1, kv0 + (t1 + 1) * 64)
                QKT(0, t1 + 1)
            }
            SMPV(1, t1)
            __syncthreads();
        }
    }

    // epilogue: store raw U (bf16) + half-total l (f32); normalization in combine
    #pragma unroll
    for (int dt = 0; dt < 2; ++dt) {
        #pragma unroll
        for (int rg = 0; rg < 4; ++rg) {
            int d0 = dt * 32 + rg * 8 + hi * 4;
            ushort4 stv;
            stv.x = f2bf(oacc[dt][rg * 4 + 0]);
            stv.y = f2bf(oacc[dt][rg * 4 + 1]);
            stv.z = f2bf(oacc[dt][rg * 4 + 2]);
            stv.w = f2bf(oacc[dt][rg * 4 + 3]);
            *reinterpret_cast<ushort4*>(Oh + (size_t)(qrow0 + qq) * 1024 + h * 64 + d0) = stv;
        }
    }
    l_sum = l_sum + __shfl_xor(l_sum, 32);
    if (hi == 0)
        lq[(qrow0 + qq) * 16 + h] = l_sum;
}

extern "C" void kernel_launch(void* const* d_in, const int* in_sizes, int n_in,
                              void* d_out, int out_size, void* d_ws, size_t ws_size,
                              hipStream_t stream)
{
    const float* x  = (const float*)d_in[0];
    const float* wq = (const float*)d_in[1];
    const float* bq = (const float*)d_in[2];
    const float* wk = (const float*)d_in[3];
    const float* bk = (const float*)d_in[4];
    const float* wv = (const float*)d_in[5];
    const float* bv = (const float*)d_in[6];
    const float* wo = (const float*)d_in[7];
    const float* bo = (const float*)d_in[8];
    float* out = (float*)d_out;

    char* ws = (char*)d_ws;
    const size_t MB = 1024 * 1024;
    unsigned short* xb   = (unsigned short*)(ws + 0);        // [4096,1024] bf16
    unsigned short* wqkv = (unsigned short*)(ws + 8 * MB);   // [3072,1024] bf16
    unsigned short* wob  = (unsigned short*)(ws + 14 * MB);  // [1024,1024] bf16
    unsigned short* Qb   = (unsigned short*)(ws + 16 * MB);  // [4096,1024] bf16 (→ Ob after attn)
    unsigned short* Kb   = (unsigned short*)(ws + 24 * MB);  // [4096,1024] bf16
    unsigned short* Vt   = (unsigned short*)(ws + 32 * MB);  // [2048,2048] bf16
    unsigned short* O0   = (unsigned short*)(ws + 40 * MB);  // [4096,1024] bf16 U-half 0
    unsigned short* O1   = (unsigned short*)(ws + 48 * MB);  // half 1
    float*          lse0 = (float*)(ws + 56 * MB);           // [2][4096,16] f32 linear l
    unsigned short* Ob   = Qb;                               // Qb dead after attn

    cvt_all<<<8192, 256, 0, stream>>>(x, wq, wk, wv, wo, xb, wqkv);   // xb + wqkv + wob

    qkv_gemm<<<1536, 256, 0, stream>>>(xb, wqkv, bq, bk, bv, Qb, Kb, Vt);
    attn_kernel<<<512, 512, 0, stream>>>(Qb, Kb, Vt, O0, O1, lse0);
    combine_kernel<<<2048, 256, 0, stream>>>(O0, O1, lse0, Ob);
    out_gemm<<<dim3(32, 16), 256, 0, stream>>>(Ob, wob, bo, out);
}

// Round 23
// 114.812 us; speedup vs baseline: 1.0700x; 1.0700x over previous
//
#include <hip/hip_runtime.h>

typedef __bf16 bf16x8 __attribute__((ext_vector_type(8)));
typedef float f32x4 __attribute__((ext_vector_type(4)));
typedef float f32x16 __attribute__((ext_vector_type(16)));

__device__ __forceinline__ unsigned short f2bf(float f) {
    unsigned u = __builtin_bit_cast(unsigned, f);
    u += 0x7FFFu + ((u >> 16) & 1u);   // RNE
    return (unsigned short)(u >> 16);
}
__device__ __forceinline__ float bf2f(unsigned short u) {
    return __builtin_bit_cast(float, (unsigned)u << 16);
}
__device__ __forceinline__ unsigned cvtpk_bf16(float lo, float hi) {
    unsigned r;
    asm("v_cvt_pk_bf16_f32 %0, %1, %2" : "=v"(r) : "v"(lo), "v"(hi));
    return r;
}
__device__ __forceinline__ float exp2_hw(float x) {
    float r;
    asm("v_exp_f32 %0, %1" : "=v"(r) : "v"(x));
    return r;
}

// async global->LDS, 16B per lane; LDS dest = wave-uniform base + lane*16
__device__ __forceinline__ void gload16(const void* g, void* l) {
    __builtin_amdgcn_global_load_lds(
        (const __attribute__((address_space(1))) void*)g,
        (__attribute__((address_space(3))) void*)l, 16, 0, 0);
}

// ---------------- fp32 -> bf16 conversion: x + all 4 weights, one launch ----------------
__global__ __launch_bounds__(256) void cvt_all(const float* __restrict__ x,
    const float* __restrict__ w0, const float* __restrict__ w1,
    const float* __restrict__ w2, const float* __restrict__ w3,
    unsigned short* __restrict__ xb, unsigned short* __restrict__ wout)
{
    int i = blockIdx.x * 256 + threadIdx.x;
    const float* src;
    unsigned short* dst;
    int j;
    if (i < 1048576) {
        src = x; dst = xb; j = i;
    } else {
        int k = i - 1048576;
        int m = k >> 18;
        src = (m == 0) ? w0 : (m == 1) ? w1 : (m == 2) ? w2 : w3;
        dst = wout + (size_t)m * 1048576;
        j = k & 262143;
    }
    float4 v = reinterpret_cast<const float4*>(src)[j];
    ushort4 o;
    o.x = f2bf(v.x); o.y = f2bf(v.y); o.z = f2bf(v.z); o.w = f2bf(v.w);
    reinterpret_cast<ushort4*>(dst)[j] = o;
}

// ---------------- fused QKV projection: BM=128 x BN=64 ----------------
// grid 1536 = 8 XCDs x (16m x 12n); each 64-col tile lies wholly in Q, K, or V.
// Q pre-scaled by 0.125*log2(e).
__global__ __launch_bounds__(256) void qkv_gemm(const unsigned short* __restrict__ X,
    const unsigned short* __restrict__ Wqkv,
    const float* __restrict__ bq, const float* __restrict__ bk, const float* __restrict__ bv,
    unsigned short* __restrict__ Qb, unsigned short* __restrict__ Kb, unsigned short* __restrict__ Vt)
{
    __shared__ __align__(16) unsigned short sA[128 * 64];   // 16 KB
    __shared__ __align__(16) unsigned short sW[64 * 64];    // 8 KB
    f32x4 acc[4][2] = {};
    const int id = blockIdx.x;
    const int xcd = id & 7, local = id >> 3;        // 1536 = 8 x 192
    const int m = (xcd & 1) * 16 + (local & 15);    // 2 m-chunks of 16
    const int n = (xcd >> 1) * 12 + (local >> 4);   // 4 n-chunks of 12
    const int m0 = m * 128, n0 = n * 64;

    const int tid  = threadIdx.x;
    const int lane = tid & 63;
    const int wv   = tid >> 6;
    const int wm   = wv >> 1, wn = wv & 1;   // 2x2 wave grid, 64x32 per wave
    const int lrow = lane >> 3;
    const int lchunk = (lane & 7) ^ lrow;

    char* sAc = reinterpret_cast<char*>(sA);
    char* sWc = reinterpret_cast<char*>(sW);

    for (int kt = 0; kt < 1024; kt += 64) {
        __syncthreads();
        #pragma unroll
        for (int j = 0; j < 4; ++j) {
            int row = (wv * 4 + j) * 8 + lrow;   // 0..127
            gload16(X + (size_t)(m0 + row) * 1024 + kt + lchunk * 8, sAc + (wv * 4 + j) * 1024);
        }
        #pragma unroll
        for (int j = 0; j < 2; ++j) {
            int row = (wv * 2 + j) * 8 + lrow;   // 0..63
            gload16(Wqkv + (size_t)(n0 + row) * 1024 + kt + lchunk * 8, sWc + (wv * 2 + j) * 1024);
        }
        __syncthreads();
        #pragma unroll
        for (int kk = 0; kk < 2; ++kk) {
            bf16x8 af[4], wf[2];
            #pragma unroll
            for (int r = 0; r < 4; ++r) {
                int rowA = wm * 64 + r * 16 + (lane & 15);
                int ca = ((kk * 4 + (lane >> 4)) ^ (rowA & 7)) * 16;
                af[r] = *reinterpret_cast<const bf16x8*>(sAc + rowA * 128 + ca);
            }
            #pragma unroll
            for (int c = 0; c < 2; ++c) {
                int rowW = wn * 32 + c * 16 + (lane & 15);
                int cw = ((kk * 4 + (lane >> 4)) ^ (rowW & 7)) * 16;
                wf[c] = *reinterpret_cast<const bf16x8*>(sWc + rowW * 128 + cw);
            }
            #pragma unroll
            for (int r = 0; r < 4; ++r)
                #pragma unroll
                for (int c = 0; c < 2; ++c)
                    acc[r][c] = __builtin_amdgcn_mfma_f32_16x16x32_bf16(af[r], wf[c], acc[r][c], 0, 0, 0);
        }
    }

    const int mid = n0 >> 10;                 // 0=Q 1=K 2=V
    const float* bias = (mid == 0) ? bq : (mid == 1) ? bk : bv;
    const float qs = (mid == 0) ? 0.18033688011112042f : 1.0f;   // 0.125*log2(e)
    #pragma unroll
    for (int r = 0; r < 4; ++r) {
        #pragma unroll
        for (int c = 0; c < 2; ++c) {
            int colg = n0 + wn * 32 + c * 16 + (lane & 15);
            int col = colg & 1023;
            float bb = bias[col];
            int row0 = m0 + wm * 64 + r * 16 + 4 * (lane >> 4);
            if (mid == 2) {
                ushort4 sv;
                sv.x = f2bf(acc[r][c][0] + bb);
                sv.y = f2bf(acc[r][c][1] + bb);
                sv.z = f2bf(acc[r][c][2] + bb);
                sv.w = f2bf(acc[r][c][3] + bb);
                *reinterpret_cast<ushort4*>(
                    Vt + ((size_t)((row0 >> 11) * 1024 + col)) * 2048 + (row0 & 2047)) = sv;
            } else {
                #pragma unroll
                for (int e = 0; e < 4; ++e) {
                    unsigned short bf = f2bf((acc[r][c][e] + bb) * qs);
                    if (mid == 0) Qb[(size_t)(row0 + e) * 1024 + col] = bf;
                    else          Kb[(size_t)(row0 + e) * 1024 + col] = bf;
                }
            }
        }
    }
}

// ---------------- output projection: BM=128 x BN=64 tiles, grid (32,16) ----------------
__global__ __launch_bounds__(256) void out_gemm(const unsigned short* __restrict__ O,
    const unsigned short* __restrict__ Wo, const float* __restrict__ bo,
    float* __restrict__ out)
{
    __shared__ __align__(16) unsigned short sA[128 * 64];   // 16 KB
    __shared__ __align__(16) unsigned short sW[64 * 64];    // 8 KB
    f32x4 acc[4][2] = {};
    const int m0 = blockIdx.x * 128, n0 = blockIdx.y * 64;

    const int tid  = threadIdx.x;
    const int lane = tid & 63;
    const int wv   = tid >> 6;
    const int wm   = wv >> 1, wn = wv & 1;   // 2x2 wave grid, 64x32 per wave
    const int lrow = lane >> 3;
    const int lchunk = (lane & 7) ^ lrow;

    char* sAc = reinterpret_cast<char*>(sA);
    char* sWc = reinterpret_cast<char*>(sW);

    for (int kt = 0; kt < 1024; kt += 64) {
        __syncthreads();
        #pragma unroll
        for (int j = 0; j < 4; ++j) {
            int row = (wv * 4 + j) * 8 + lrow;   // 0..127
            gload16(O + (size_t)(m0 + row) * 1024 + kt + lchunk * 8, sAc + (wv * 4 + j) * 1024);
        }
        #pragma unroll
        for (int j = 0; j < 2; ++j) {
            int row = (wv * 2 + j) * 8 + lrow;   // 0..63
            gload16(Wo + (size_t)(n0 + row) * 1024 + kt + lchunk * 8, sWc + (wv * 2 + j) * 1024);
        }
        __syncthreads();
        #pragma unroll
        for (int kk = 0; kk < 2; ++kk) {
            bf16x8 af[4], wf[2];
            #pragma unroll
            for (int r = 0; r < 4; ++r) {
                int rowA = wm * 64 + r * 16 + (lane & 15);
                int ca = ((kk * 4 + (lane >> 4)) ^ (rowA & 7)) * 16;
                af[r] = *reinterpret_cast<const bf16x8*>(sAc + rowA * 128 + ca);
            }
            #pragma unroll
            for (int c = 0; c < 2; ++c) {
                int rowW = wn * 32 + c * 16 + (lane & 15);
                int cw = ((kk * 4 + (lane >> 4)) ^ (rowW & 7)) * 16;
                wf[c] = *reinterpret_cast<const bf16x8*>(sWc + rowW * 128 + cw);
            }
            #pragma unroll
            for (int r = 0; r < 4; ++r)
                #pragma unroll
                for (int c = 0; c < 2; ++c)
                    acc[r][c] = __builtin_amdgcn_mfma_f32_16x16x32_bf16(af[r], wf[c], acc[r][c], 0, 0, 0);
        }
    }

    #pragma unroll
    for (int r = 0; r < 4; ++r) {
        #pragma unroll
        for (int c = 0; c < 2; ++c) {
            int col = n0 + wn * 32 + c * 16 + (lane & 15);
            float bb = bo[col];
            #pragma unroll
            for (int e = 0; e < 4; ++e) {
                int row = m0 + wm * 64 + r * 16 + 4 * (lane >> 4) + e;
                out[(size_t)row * 1024 + col] = acc[r][c][e] + bb;
            }
        }
    }
}

// ---------------- merge the two kv-halves (linear weights, shared zero shift) ----------------
__global__ __launch_bounds__(256) void combine_kernel(
    const unsigned short* __restrict__ O0, const unsigned short* __restrict__ O1,
    const float* __restrict__ lbase, unsigned short* __restrict__ Ob)
{
    int idx = blockIdx.x * 256 + threadIdx.x;
    int row = idx >> 7;              // 128 uint4 per row of 1024
    int h = (idx & 127) >> 3;        // 8 uint4 per head
    float lsum = lbase[row * 16 + h] + lbase[65536 + row * 16 + h];
    float inv = 1.0f / lsum;
    uint4 x0 = reinterpret_cast<const uint4*>(O0)[idx];
    uint4 x1 = reinterpret_cast<const uint4*>(O1)[idx];
    const unsigned* p0 = reinterpret_cast<const unsigned*>(&x0);
    const unsigned* p1 = reinterpret_cast<const unsigned*>(&x1);
    uint4 o;
    unsigned* po = reinterpret_cast<unsigned*>(&o);
    #pragma unroll
    for (int wd = 0; wd < 4; ++wd) {
        float lo = bf2f((unsigned short)(p0[wd] & 0xFFFF)) + bf2f((unsigned short)(p1[wd] & 0xFFFF));
        float hi = bf2f((unsigned short)(p0[wd] >> 16)) + bf2f((unsigned short)(p1[wd] >> 16));
        po[wd] = cvtpk_bf16(lo * inv, hi * inv);
    }
    reinterpret_cast<uint4*>(Ob)[idx] = o;
}

// ---------------- flash attention, kv-split x2, LDS-staged, 8-wave blocks ----------------
// grid 512 blocks of 512 threads, XCD-swizzled. Wave owns 32 Q rows (block = 256 q rows);
// 16 kv-tiles of 64 per half. p = exp2(S2) raw (shift-free); emits unnormalized U + linear l.
__global__ __launch_bounds__(512) void attn_kernel(const unsigned short* __restrict__ Qb,
    const unsigned short* __restrict__ Kb, const unsigned short* __restrict__ Vt,
    unsigned short* __restrict__ Oq0, unsigned short* __restrict__ Oq1,
    float* __restrict__ lbase)
{
    __shared__ __align__(16) unsigned short sK[2][64 * 64];   // [buf][kv][d]
    __shared__ __align__(16) unsigned short sV[2][64 * 64];   // [buf][d][kv]

    const int id = blockIdx.x;
    const int swz = (id & 7) * 64 + (id >> 3);          // bijective (512%8==0)
    const int qt = swz & 7;                             // 8 q-tiles of 256 rows
    const int bh = (swz >> 3) & 31;
    const int half = swz >> 8;                          // 0 or 1
    const int b = bh >> 4, h = bh & 15;
    const int tid = threadIdx.x, lane = tid & 63, wv = tid >> 6;   // wv 0..7
    const int qq = lane & 31, hi = lane >> 5;

    unsigned short* Oh = half ? Oq1 : Oq0;
    float* lq = lbase + half * 65536;

    const int qrow0 = b * 2048 + qt * 256 + wv * 32;
    const int kv0 = half * 1024;
    const int ntiles = 16;                   // 2048/2 kv rows / 64

    bf16x8 qf[4];
    #pragma unroll
    for (int ks = 0; ks < 4; ++ks)
        qf[ks] = *reinterpret_cast<const bf16x8*>(
            Qb + (size_t)(qrow0 + qq) * 1024 + h * 64 + ks * 16 + hi * 8);

    f32x16 oacc[2] = {};           // U^T: rows d, col q=qq (unnormalized)
    float l_sum = 0.f;

    const unsigned short* Kbase = Kb + (size_t)b * 2048 * 1024 + h * 64;
    const unsigned short* Vbase = Vt + (size_t)(bh * 64) * 2048;

    const int lrow = lane >> 3;              // 0..7
    const int lchunk = (lane & 7) ^ lrow;    // pre-swizzled source chunk

    char* sKbase = reinterpret_cast<char*>(sK);
    char* sVbase = reinterpret_cast<char*>(sV);

    // 8 waves x 8 rows = 64 rows; 1 gload16 per thread per matrix
    #define FILL(buf, kvoff)                                                              \
        {                                                                                 \
            int row = wv * 8 + lrow;                                                      \
            gload16(Kbase + (size_t)((kvoff) + row) * 1024 + lchunk * 8,                  \
                    sKbase + (buf) * 8192 + wv * 1024);                                   \
            gload16(Vbase + (size_t)row * 2048 + (kvoff) + lchunk * 8,                    \
                    sVbase + (buf) * 8192 + wv * 1024);                                   \
        }

    FILL(0, kv0)
    __syncthreads();

    for (int t = 0; t < ntiles; ++t) {
        const int cur = t & 1;
        if (t < ntiles - 1) { FILL(cur ^ 1, kv0 + (t + 1) * 64) }

        const char* bK = sKbase + cur * 8192;
        const char* bV = sVbase + cur * 8192;

        // S^T[kv][q] = K x Q (log2 domain)
        f32x16 pacc[2];
        __builtin_amdgcn_s_setprio(1);
        #pragma unroll
        for (int mt = 0; mt < 2; ++mt) {
            f32x16 acc = {};
            int row = mt * 32 + qq;
            #pragma unroll
            for (int ks = 0; ks < 4; ++ks) {
                int c = ((ks * 2 + hi) ^ (row & 7)) * 16;
                bf16x8 kf = *reinterpret_cast<const bf16x8*>(bK + row * 128 + c);
                acc = __builtin_amdgcn_mfma_f32_32x32x16_bf16(kf, qf[ks], acc, 0, 0, 0);
            }
            pacc[mt] = acc;
        }
        __builtin_amdgcn_s_setprio(0);

        // shift-free softmax: p = exp2(S2); 4 independent partial sums
        float rs0 = 0.f, rs1 = 0.f, rs2 = 0.f, rs3 = 0.f;
        #pragma unroll
        for (int mt = 0; mt < 2; ++mt) {
            #pragma unroll
            for (int r = 0; r < 16; r += 4) {
                float p0 = exp2_hw(pacc[mt][r + 0]);
                float p1 = exp2_hw(pacc[mt][r + 1]);
                float p2 = exp2_hw(pacc[mt][r + 2]);
                float p3 = exp2_hw(pacc[mt][r + 3]);
                pacc[mt][r + 0] = p0; rs0 += p0;
                pacc[mt][r + 1] = p1; rs1 += p1;
                pacc[mt][r + 2] = p2; rs2 += p2;
                pacc[mt][r + 3] = p3; rs3 += p3;
            }
        }
        l_sum += (rs0 + rs1) + (rs2 + rs3);

        // P^T -> bf16 B-fragments via cvt_pk + shfl_xor(32) half-exchange, then PV
        __builtin_amdgcn_s_setprio(1);
        #pragma unroll
        for (int mt = 0; mt < 2; ++mt) {
            #pragma unroll
            for (int halfk = 0; halfk < 2; ++halfk) {
                int r0 = halfk * 8;
                unsigned A0 = cvtpk_bf16(pacc[mt][r0 + 0], pacc[mt][r0 + 1]);
                unsigned A1 = cvtpk_bf16(pacc[mt][r0 + 2], pacc[mt][r0 + 3]);
                unsigned B0 = cvtpk_bf16(pacc[mt][r0 + 4], pacc[mt][r0 + 5]);
                unsigned B1 = cvtpk_bf16(pacc[mt][r0 + 6], pacc[mt][r0 + 7]);
                unsigned t0 = hi ? A0 : B0;
                unsigned t1 = hi ? A1 : B1;
                unsigned r0x = (unsigned)__shfl_xor((int)t0, 32);
                unsigned r1x = (unsigned)__shfl_xor((int)t1, 32);
                union { unsigned u[4]; bf16x8 v; } pf;
                pf.u[0] = hi ? r0x : A0;
                pf.u[1] = hi ? r1x : A1;
                pf.u[2] = hi ? B0 : r0x;
                pf.u[3] = hi ? B1 : r1x;
                int ks = mt * 2 + halfk;
                #pragma unroll
                for (int dt = 0; dt < 2; ++dt) {
                    int row = dt * 32 + qq;
                    int c = ((ks * 2 + hi) ^ (row & 7)) * 16;
                    bf16x8 vf = *reinterpret_cast<const bf16x8*>(bV + row * 128 + c);
                    oacc[dt] = __builtin_amdgcn_mfma_f32_32x32x16_bf16(vf, pf.v, oacc[dt], 0, 0, 0);
                }
            }
        }
        __builtin_amdgcn_s_setprio(0);
        __syncthreads();
    }

    // epilogue: store raw U (bf16) + half-total l (f32); normalization in combine
    #pragma unroll
    for (int dt = 0; dt < 2; ++dt) {
        #pragma unroll
        for (int rg = 0; rg < 4; ++rg) {
            int d0 = dt * 32 + rg * 8 + hi * 4;
            ushort4 stv;
            stv.x = f2bf(oacc[dt][rg * 4 + 0]);
            stv.y = f2bf(oacc[dt][rg * 4 + 1]);
            stv.z = f2bf(oacc[dt][rg * 4 + 2]);
            stv.w = f2bf(oacc[dt][rg * 4 + 3]);
            *reinterpret_cast<ushort4*>(Oh + (size_t)(qrow0 + qq) * 1024 + h * 64 + d0) = stv;
        }
    }
    l_sum = l_sum + __shfl_xor(l_sum, 32);
    if (hi == 0)
        lq[(qrow0 + qq) * 16 + h] = l_sum;
}

extern "C" void kernel_launch(void* const* d_in, const int* in_sizes, int n_in,
                              void* d_out, int out_size, void* d_ws, size_t ws_size,
                              hipStream_t stream)
{
    const float* x  = (const float*)d_in[0];
    const float* wq = (const float*)d_in[1];
    const float* bq = (const float*)d_in[2];
    const float* wk = (const float*)d_in[3];
    const float* bk = (const float*)d_in[4];
    const float* wv = (const float*)d_in[5];
    const float* bv = (const float*)d_in[6];
    const float* wo = (const float*)d_in[7];
    const float* bo = (const float*)d_in[8];
    float* out = (float*)d_out;

    char* ws = (char*)d_ws;
    const size_t MB = 1024 * 1024;
    unsigned short* xb   = (unsigned short*)(ws + 0);        // [4096,1024] bf16
    unsigned short* wqkv = (unsigned short*)(ws + 8 * MB);   // [3072,1024] bf16
    unsigned short* wob  = (unsigned short*)(ws + 14 * MB);  // [1024,1024] bf16
    unsigned short* Qb   = (unsigned short*)(ws + 16 * MB);  // [4096,1024] bf16 (→ Ob after attn)
    unsigned short* Kb   = (unsigned short*)(ws + 24 * MB);  // [4096,1024] bf16
    unsigned short* Vt   = (unsigned short*)(ws + 32 * MB);  // [2048,2048] bf16
    unsigned short* O0   = (unsigned short*)(ws + 40 * MB);  // [4096,1024] bf16 U-half 0
    unsigned short* O1   = (unsigned short*)(ws + 48 * MB);  // half 1
    float*          lse0 = (float*)(ws + 56 * MB);           // [2][4096,16] f32 linear l
    unsigned short* Ob   = Qb;                               // Qb dead after attn

    cvt_all<<<8192, 256, 0, stream>>>(x, wq, wk, wv, wo, xb, wqkv);   // xb + wqkv + wob

    qkv_gemm<<<1536, 256, 0, stream>>>(xb, wqkv, bq, bk, bv, Qb, Kb, Vt);
    attn_kernel<<<512, 512, 0, stream>>>(Qb, Kb, Vt, O0, O1, lse0);
    combine_kernel<<<2048, 256, 0, stream>>>(O0, O1, lse0, Ob);
    out_gemm<<<dim3(32, 16), 256, 0, stream>>>(Ob, wob, bo, out);
}

// Round 24
// 114.697 us; speedup vs baseline: 1.0711x; 1.0010x over previous
//
#include <hip/hip_runtime.h>

typedef __bf16 bf16x8 __attribute__((ext_vector_type(8)));
typedef float f32x4 __attribute__((ext_vector_type(4)));
typedef float f32x16 __attribute__((ext_vector_type(16)));

__device__ __forceinline__ unsigned short f2bf(float f) {
    unsigned u = __builtin_bit_cast(unsigned, f);
    u += 0x7FFFu + ((u >> 16) & 1u);   // RNE
    return (unsigned short)(u >> 16);
}
__device__ __forceinline__ float bf2f(unsigned short u) {
    return __builtin_bit_cast(float, (unsigned)u << 16);
}
__device__ __forceinline__ unsigned cvtpk_bf16(float lo, float hi) {
    unsigned r;
    asm("v_cvt_pk_bf16_f32 %0, %1, %2" : "=v"(r) : "v"(lo), "v"(hi));
    return r;
}
__device__ __forceinline__ float exp2_hw(float x) {
    float r;
    asm("v_exp_f32 %0, %1" : "=v"(r) : "v"(x));
    return r;
}

// async global->LDS, 16B per lane; LDS dest = wave-uniform base + lane*16
__device__ __forceinline__ void gload16(const void* g, void* l) {
    __builtin_amdgcn_global_load_lds(
        (const __attribute__((address_space(1))) void*)g,
        (__attribute__((address_space(3))) void*)l, 16, 0, 0);
}

// ---------------- fp32 -> bf16 conversion: x + all 4 weights, one launch ----------------
__global__ __launch_bounds__(256) void cvt_all(const float* __restrict__ x,
    const float* __restrict__ w0, const float* __restrict__ w1,
    const float* __restrict__ w2, const float* __restrict__ w3,
    unsigned short* __restrict__ xb, unsigned short* __restrict__ wout)
{
    int i = blockIdx.x * 256 + threadIdx.x;
    const float* src;
    unsigned short* dst;
    int j;
    if (i < 1048576) {
        src = x; dst = xb; j = i;
    } else {
        int k = i - 1048576;
        int m = k >> 18;
        src = (m == 0) ? w0 : (m == 1) ? w1 : (m == 2) ? w2 : w3;
        dst = wout + (size_t)m * 1048576;
        j = k & 262143;
    }
    float4 v = reinterpret_cast<const float4*>(src)[j];
    ushort4 o;
    o.x = f2bf(v.x); o.y = f2bf(v.y); o.z = f2bf(v.z); o.w = f2bf(v.w);
    reinterpret_cast<ushort4*>(dst)[j] = o;
}

// ---------------- fused QKV projection: BM=128 x BN=64 ----------------
// grid 1536 = 8 XCDs x (16m x 12n); each 64-col tile lies wholly in Q, K, or V.
// Q pre-scaled by 0.125*log2(e).
__global__ __launch_bounds__(256) void qkv_gemm(const unsigned short* __restrict__ X,
    const unsigned short* __restrict__ Wqkv,
    const float* __restrict__ bq, const float* __restrict__ bk, const float* __restrict__ bv,
    unsigned short* __restrict__ Qb, unsigned short* __restrict__ Kb, unsigned short* __restrict__ Vt)
{
    __shared__ __align__(16) unsigned short sA[128 * 64];   // 16 KB
    __shared__ __align__(16) unsigned short sW[64 * 64];    // 8 KB
    f32x4 acc[4][2] = {};
    const int id = blockIdx.x;
    const int xcd = id & 7, local = id >> 3;        // 1536 = 8 x 192
    const int m = (xcd & 1) * 16 + (local & 15);    // 2 m-chunks of 16
    const int n = (xcd >> 1) * 12 + (local >> 4);   // 4 n-chunks of 12
    const int m0 = m * 128, n0 = n * 64;

    const int tid  = threadIdx.x;
    const int lane = tid & 63;
    const int wv   = tid >> 6;
    const int wm   = wv >> 1, wn = wv & 1;   // 2x2 wave grid, 64x32 per wave
    const int lrow = lane >> 3;
    const int lchunk = (lane & 7) ^ lrow;

    char* sAc = reinterpret_cast<char*>(sA);
    char* sWc = reinterpret_cast<char*>(sW);

    for (int kt = 0; kt < 1024; kt += 64) {
        __syncthreads();
        #pragma unroll
        for (int j = 0; j < 4; ++j) {
            int row = (wv * 4 + j) * 8 + lrow;   // 0..127
            gload16(X + (size_t)(m0 + row) * 1024 + kt + lchunk * 8, sAc + (wv * 4 + j) * 1024);
        }
        #pragma unroll
        for (int j = 0; j < 2; ++j) {
            int row = (wv * 2 + j) * 8 + lrow;   // 0..63
            gload16(Wqkv + (size_t)(n0 + row) * 1024 + kt + lchunk * 8, sWc + (wv * 2 + j) * 1024);
        }
        __syncthreads();
        #pragma unroll
        for (int kk = 0; kk < 2; ++kk) {
            bf16x8 af[4], wf[2];
            #pragma unroll
            for (int r = 0; r < 4; ++r) {
                int rowA = wm * 64 + r * 16 + (lane & 15);
                int ca = ((kk * 4 + (lane >> 4)) ^ (rowA & 7)) * 16;
                af[r] = *reinterpret_cast<const bf16x8*>(sAc + rowA * 128 + ca);
            }
            #pragma unroll
            for (int c = 0; c < 2; ++c) {
                int rowW = wn * 32 + c * 16 + (lane & 15);
                int cw = ((kk * 4 + (lane >> 4)) ^ (rowW & 7)) * 16;
                wf[c] = *reinterpret_cast<const bf16x8*>(sWc + rowW * 128 + cw);
            }
            #pragma unroll
            for (int r = 0; r < 4; ++r)
                #pragma unroll
                for (int c = 0; c < 2; ++c)
                    acc[r][c] = __builtin_amdgcn_mfma_f32_16x16x32_bf16(af[r], wf[c], acc[r][c], 0, 0, 0);
        }
    }

    const int mid = n0 >> 10;                 // 0=Q 1=K 2=V
    const float* bias = (mid == 0) ? bq : (mid == 1) ? bk : bv;
    const float qs = (mid == 0) ? 0.18033688011112042f : 1.0f;   // 0.125*log2(e)
    #pragma unroll
    for (int r = 0; r < 4; ++r) {
        #pragma unroll
        for (int c = 0; c < 2; ++c) {
            int colg = n0 + wn * 32 + c * 16 + (lane & 15);
            int col = colg & 1023;
            float bb = bias[col];
            int row0 = m0 + wm * 64 + r * 16 + 4 * (lane >> 4);
            if (mid == 2) {
                ushort4 sv;
                sv.x = f2bf(acc[r][c][0] + bb);
                sv.y = f2bf(acc[r][c][1] + bb);
                sv.z = f2bf(acc[r][c][2] + bb);
                sv.w = f2bf(acc[r][c][3] + bb);
                *reinterpret_cast<ushort4*>(
                    Vt + ((size_t)((row0 >> 11) * 1024 + col)) * 2048 + (row0 & 2047)) = sv;
            } else {
                #pragma unroll
                for (int e = 0; e < 4; ++e) {
                    unsigned short bf = f2bf((acc[r][c][e] + bb) * qs);
                    if (mid == 0) Qb[(size_t)(row0 + e) * 1024 + col] = bf;
                    else          Kb[(size_t)(row0 + e) * 1024 + col] = bf;
                }
            }
        }
    }
}

// ---------------- output projection: BM=128 x BN=64 tiles, grid (32,16) ----------------
__global__ __launch_bounds__(256) void out_gemm(const unsigned short* __restrict__ O,
    const unsigned short* __restrict__ Wo, const float* __restrict__ bo,
    float* __restrict__ out)
{
    __shared__ __align__(16) unsigned short sA[128 * 64];   // 16 KB
    __shared__ __align__(16) unsigned short sW[64 * 64];    // 8 KB
    f32x4 acc[4][2] = {};
    const int m0 = blockIdx.x * 128, n0 = blockIdx.y * 64;

    const int tid  = threadIdx.x;
    const int lane = tid & 63;
    const int wv   = tid >> 6;
    const int wm   = wv >> 1, wn = wv & 1;   // 2x2 wave grid, 64x32 per wave
    const int lrow = lane >> 3;
    const int lchunk = (lane & 7) ^ lrow;

    char* sAc = reinterpret_cast<char*>(sA);
    char* sWc = reinterpret_cast<char*>(sW);

    for (int kt = 0; kt < 1024; kt += 64) {
        __syncthreads();
        #pragma unroll
        for (int j = 0; j < 4; ++j) {
            int row = (wv * 4 + j) * 8 + lrow;   // 0..127
            gload16(O + (size_t)(m0 + row) * 1024 + kt + lchunk * 8, sAc + (wv * 4 + j) * 1024);
        }
        #pragma unroll
        for (int j = 0; j < 2; ++j) {
            int row = (wv * 2 + j) * 8 + lrow;   // 0..63
            gload16(Wo + (size_t)(n0 + row) * 1024 + kt + lchunk * 8, sWc + (wv * 2 + j) * 1024);
        }
        __syncthreads();
        #pragma unroll
        for (int kk = 0; kk < 2; ++kk) {
            bf16x8 af[4], wf[2];
            #pragma unroll
            for (int r = 0; r < 4; ++r) {
                int rowA = wm * 64 + r * 16 + (lane & 15);
                int ca = ((kk * 4 + (lane >> 4)) ^ (rowA & 7)) * 16;
                af[r] = *reinterpret_cast<const bf16x8*>(sAc + rowA * 128 + ca);
            }
            #pragma unroll
            for (int c = 0; c < 2; ++c) {
                int rowW = wn * 32 + c * 16 + (lane & 15);
                int cw = ((kk * 4 + (lane >> 4)) ^ (rowW & 7)) * 16;
                wf[c] = *reinterpret_cast<const bf16x8*>(sWc + rowW * 128 + cw);
            }
            #pragma unroll
            for (int r = 0; r < 4; ++r)
                #pragma unroll
                for (int c = 0; c < 2; ++c)
                    acc[r][c] = __builtin_amdgcn_mfma_f32_16x16x32_bf16(af[r], wf[c], acc[r][c], 0, 0, 0);
        }
    }

    #pragma unroll
    for (int r = 0; r < 4; ++r) {
        #pragma unroll
        for (int c = 0; c < 2; ++c) {
            int col = n0 + wn * 32 + c * 16 + (lane & 15);
            float bb = bo[col];
            #pragma unroll
            for (int e = 0; e < 4; ++e) {
                int row = m0 + wm * 64 + r * 16 + 4 * (lane >> 4) + e;
                out[(size_t)row * 1024 + col] = acc[r][c][e] + bb;
            }
        }
    }
}

// ---------------- merge the two kv-halves (linear weights, shared zero shift) ----------------
__global__ __launch_bounds__(256) void combine_kernel(
    const unsigned short* __restrict__ O0, const unsigned short* __restrict__ O1,
    const float* __restrict__ lbase, unsigned short* __restrict__ Ob)
{
    int idx = blockIdx.x * 256 + threadIdx.x;
    int row = idx >> 7;              // 128 uint4 per row of 1024
    int h = (idx & 127) >> 3;        // 8 uint4 per head
    float lsum = lbase[row * 16 + h] + lbase[65536 + row * 16 + h];
    float inv = 1.0f / lsum;
    uint4 x0 = reinterpret_cast<const uint4*>(O0)[idx];
    uint4 x1 = reinterpret_cast<const uint4*>(O1)[idx];
    const unsigned* p0 = reinterpret_cast<const unsigned*>(&x0);
    const unsigned* p1 = reinterpret_cast<const unsigned*>(&x1);
    uint4 o;
    unsigned* po = reinterpret_cast<unsigned*>(&o);
    #pragma unroll
    for (int wd = 0; wd < 4; ++wd) {
        float lo = bf2f((unsigned short)(p0[wd] & 0xFFFF)) + bf2f((unsigned short)(p1[wd] & 0xFFFF));
        float hi = bf2f((unsigned short)(p0[wd] >> 16)) + bf2f((unsigned short)(p1[wd] >> 16));
        po[wd] = cvtpk_bf16(lo * inv, hi * inv);
    }
    reinterpret_cast<uint4*>(Ob)[idx] = o;
}

// ---------------- flash attention, kv-split x2, LDS-staged, 8-wave blocks ----------------
// grid 512 blocks of 512 threads, XCD-swizzled. Wave owns 32 Q rows (block = 256 q rows);
// 16 kv-tiles of 64 per half. p = exp2(S2) raw (shift-free); emits unnormalized U + linear l.
__global__ __launch_bounds__(512) void attn_kernel(const unsigned short* __restrict__ Qb,
    const unsigned short* __restrict__ Kb, const unsigned short* __restrict__ Vt,
    unsigned short* __restrict__ Oq0, unsigned short* __restrict__ Oq1,
    float* __restrict__ lbase)
{
    __shared__ __align__(16) unsigned short sK[2][64 * 64];   // [buf][kv][d]
    __shared__ __align__(16) unsigned short sV[2][64 * 64];   // [buf][d][kv]

    const int id = blockIdx.x;
    const int swz = (id & 7) * 64 + (id >> 3);          // bijective (512%8==0)
    const int qt = swz & 7;                             // 8 q-tiles of 256 rows
    const int bh = (swz >> 3) & 31;
    const int half = swz >> 8;                          // 0 or 1
    const int b = bh >> 4, h = bh & 15;
    const int tid = threadIdx.x, lane = tid & 63, wv = tid >> 6;   // wv 0..7
    const int qq = lane & 31, hi = lane >> 5;

    unsigned short* Oh = half ? Oq1 : Oq0;
    float* lq = lbase + half * 65536;

    const int qrow0 = b * 2048 + qt * 256 + wv * 32;
    const int kv0 = half * 1024;
    const int ntiles = 16;                   // 2048/2 kv rows / 64

    bf16x8 qf[4];
    #pragma unroll
    for (int ks = 0; ks < 4; ++ks)
        qf[ks] = *reinterpret_cast<const bf16x8*>(
            Qb + (size_t)(qrow0 + qq) * 1024 + h * 64 + ks * 16 + hi * 8);

    f32x16 oacc[2] = {};           // U^T: rows d, col q=qq (unnormalized)
    float l_sum = 0.f;

    const unsigned short* Kbase = Kb + (size_t)b * 2048 * 1024 + h * 64;
    const unsigned short* Vbase = Vt + (size_t)(bh * 64) * 2048;

    const int lrow = lane >> 3;              // 0..7
    const int lchunk = (lane & 7) ^ lrow;    // pre-swizzled source chunk

    char* sKbase = reinterpret_cast<char*>(sK);
    char* sVbase = reinterpret_cast<char*>(sV);

    // 8 waves x 8 rows = 64 rows; 1 gload16 per thread per matrix
    #define FILL(buf, kvoff)                                                              \
        {                                                                                 \
            int row = wv * 8 + lrow;                                                      \
            gload16(Kbase + (size_t)((kvoff) + row) * 1024 + lchunk * 8,                  \
                    sKbase + (buf) * 8192 + wv * 1024);                                   \
            gload16(Vbase + (size_t)row * 2048 + (kvoff) + lchunk * 8,                    \
                    sVbase + (buf) * 8192 + wv * 1024);                                   \
        }

    FILL(0, kv0)
    __syncthreads();

    for (int t = 0; t < ntiles; ++t) {
        const int cur = t & 1;
        if (t < ntiles - 1) { FILL(cur ^ 1, kv0 + (t + 1) * 64) }

        const char* bK = sKbase + cur * 8192;
        const char* bV = sVbase + cur * 8192;

        // S^T[kv][q] = K x Q (log2 domain)
        f32x16 pacc[2];
        __builtin_amdgcn_s_setprio(1);
        #pragma unroll
        for (int mt = 0; mt < 2; ++mt) {
            f32x16 acc = {};
            int row = mt * 32 + qq;
            #pragma unroll
            for (int ks = 0; ks < 4; ++ks) {
                int c = ((ks * 2 + hi) ^ (row & 7)) * 16;
                bf16x8 kf = *reinterpret_cast<const bf16x8*>(bK + row * 128 + c);
                acc = __builtin_amdgcn_mfma_f32_32x32x16_bf16(kf, qf[ks], acc, 0, 0, 0);
            }
            pacc[mt] = acc;
        }
        __builtin_amdgcn_s_setprio(0);

        // shift-free softmax: p = exp2(S2); 4 independent partial sums
        float rs0 = 0.f, rs1 = 0.f, rs2 = 0.f, rs3 = 0.f;
        #pragma unroll
        for (int mt = 0; mt < 2; ++mt) {
            #pragma unroll
            for (int r = 0; r < 16; r += 4) {
                float p0 = exp2_hw(pacc[mt][r + 0]);
                float p1 = exp2_hw(pacc[mt][r + 1]);
                float p2 = exp2_hw(pacc[mt][r + 2]);
                float p3 = exp2_hw(pacc[mt][r + 3]);
                pacc[mt][r + 0] = p0; rs0 += p0;
                pacc[mt][r + 1] = p1; rs1 += p1;
                pacc[mt][r + 2] = p2; rs2 += p2;
                pacc[mt][r + 3] = p3; rs3 += p3;
            }
        }
        l_sum += (rs0 + rs1) + (rs2 + rs3);

        // P^T -> bf16 B-fragments via cvt_pk + shfl_xor(32) half-exchange, then PV
        __builtin_amdgcn_s_setprio(1);
        #pragma unroll
        for (int mt = 0; mt < 2; ++mt) {
            #pragma unroll
            for (int halfk = 0; halfk < 2; ++halfk) {
                int r0 = halfk * 8;
                unsigned A0 = cvtpk_bf16(pacc[mt][r0 + 0], pacc[mt][r0 + 1]);
                unsigned A1 = cvtpk_bf16(pacc[mt][r0 + 2], pacc[mt][r0 + 3]);
                unsigned B0 = cvtpk_bf16(pacc[mt][r0 + 4], pacc[mt][r0 + 5]);
                unsigned B1 = cvtpk_bf16(pacc[mt][r0 + 6], pacc[mt][r0 + 7]);
                unsigned t0 = hi ? A0 : B0;
                unsigned t1 = hi ? A1 : B1;
                unsigned r0x = (unsigned)__shfl_xor((int)t0, 32);
                unsigned r1x = (unsigned)__shfl_xor((int)t1, 32);
                union { unsigned u[4]; bf16x8 v; } pf;
                pf.u[0] = hi ? r0x : A0;
                pf.u[1] = hi ? r1x : A1;
                pf.u[2] = hi ? B0 : r0x;
                pf.u[3] = hi ? B1 : r1x;
                int ks = mt * 2 + halfk;
                #pragma unroll
                for (int dt = 0; dt < 2; ++dt) {
                    int row = dt * 32 + qq;
                    int c = ((ks * 2 + hi) ^ (row & 7)) * 16;
                    bf16x8 vf = *reinterpret_cast<const bf16x8*>(bV + row * 128 + c);
                    oacc[dt] = __builtin_amdgcn_mfma_f32_32x32x16_bf16(vf, pf.v, oacc[dt], 0, 0, 0);
                }
            }
        }
        __builtin_amdgcn_s_setprio(0);
        __syncthreads();
    }

    // epilogue: store raw U (bf16) + half-total l (f32); normalization in combine
    #pragma unroll
    for (int dt = 0; dt < 2; ++dt) {
        #pragma unroll
        for (int rg = 0; rg < 4; ++rg) {
            int d0 = dt * 32 + rg * 8 + hi * 4;
            ushort4 stv;
            stv.x = f2bf(oacc[dt][rg * 4 + 0]);
            stv.y = f2bf(oacc[dt][rg * 4 + 1]);
            stv.z = f2bf(oacc[dt][rg * 4 + 2]);
            stv.w = f2bf(oacc[dt][rg * 4 + 3]);
            *reinterpret_cast<ushort4*>(Oh + (size_t)(qrow0 + qq) * 1024 + h * 64 + d0) = stv;
        }
    }
    l_sum = l_sum + __shfl_xor(l_sum, 32);
    if (hi == 0)
        lq[(qrow0 + qq) * 16 + h] = l_sum;
}

extern "C" void kernel_launch(void* const* d_in, const int* in_sizes, int n_in,
                              void* d_out, int out_size, void* d_ws, size_t ws_size,
                              hipStream_t stream)
{
    const float* x  = (const float*)d_in[0];
    const float* wq = (const float*)d_in[1];
    const float* bq = (const float*)d_in[2];
    const float* wk = (const float*)d_in[3];
    const float* bk = (const float*)d_in[4];
    const float* wv = (const float*)d_in[5];
    const float* bv = (const float*)d_in[6];
    const float* wo = (const float*)d_in[7];
    const float* bo = (const float*)d_in[8];
    float* out = (float*)d_out;

    char* ws = (char*)d_ws;
    const size_t MB = 1024 * 1024;
    unsigned short* xb   = (unsigned short*)(ws + 0);        // [4096,1024] bf16
    unsigned short* wqkv = (unsigned short*)(ws + 8 * MB);   // [3072,1024] bf16
    unsigned short* wob  = (unsigned short*)(ws + 14 * MB);  // [1024,1024] bf16
    unsigned short* Qb   = (unsigned short*)(ws + 16 * MB);  // [4096,1024] bf16 (→ Ob after attn)
    unsigned short* Kb   = (unsigned short*)(ws + 24 * MB);  // [4096,1024] bf16
    unsigned short* Vt   = (unsigned short*)(ws + 32 * MB);  // [2048,2048] bf16
    unsigned short* O0   = (unsigned short*)(ws + 40 * MB);  // [4096,1024] bf16 U-half 0
    unsigned short* O1   = (unsigned short*)(ws + 48 * MB);  // half 1
    float*          lse0 = (float*)(ws + 56 * MB);           // [2][4096,16] f32 linear l
    unsigned short* Ob   = Qb;                               // Qb dead after attn

    cvt_all<<<8192, 256, 0, stream>>>(x, wq, wk, wv, wo, xb, wqkv);   // xb + wqkv + wob

    qkv_gemm<<<1536, 256, 0, stream>>>(xb, wqkv, bq, bk, bv, Qb, Kb, Vt);
    attn_kernel<<<512, 512, 0, stream>>>(Qb, Kb, Vt, O0, O1, lse0);
    combine_kernel<<<2048, 256, 0, stream>>>(O0, O1, lse0, Ob);
    out_gemm<<<dim3(32, 16), 256, 0, stream>>>(Ob, wob, bo, out);
}

// Round 26
// 114.470 us; speedup vs baseline: 1.0732x; 1.0020x over previous
//
#include <hip/hip_runtime.h>

typedef __bf16 bf16x8 __attribute__((ext_vector_type(8)));
typedef float f32x4 __attribute__((ext_vector_type(4)));
typedef float f32x16 __attribute__((ext_vector_type(16)));

__device__ __forceinline__ unsigned short f2bf(float f) {
    unsigned u = __builtin_bit_cast(unsigned, f);
    u += 0x7FFFu + ((u >> 16) & 1u);   // RNE
    return (unsigned short)(u >> 16);
}
__device__ __forceinline__ float bf2f(unsigned short u) {
    return __builtin_bit_cast(float, (unsigned)u << 16);
}
__device__ __forceinline__ unsigned cvtpk_bf16(float lo, float hi) {
    unsigned r;
    asm("v_cvt_pk_bf16_f32 %0, %1, %2" : "=v"(r) : "v"(lo), "v"(hi));
    return r;
}
__device__ __forceinline__ float exp2_hw(float x) {
    float r;
    asm("v_exp_f32 %0, %1" : "=v"(r) : "v"(x));
    return r;
}

// async global->LDS, 16B per lane; LDS dest = wave-uniform base + lane*16
__device__ __forceinline__ void gload16(const void* g, void* l) {
    __builtin_amdgcn_global_load_lds(
        (const __attribute__((address_space(1))) void*)g,
        (__attribute__((address_space(3))) void*)l, 16, 0, 0);
}

// ---------------- fp32 -> bf16 conversion: x + all 4 weights, one launch ----------------
__global__ __launch_bounds__(256) void cvt_all(const float* __restrict__ x,
    const float* __restrict__ w0, const float* __restrict__ w1,
    const float* __restrict__ w2, const float* __restrict__ w3,
    unsigned short* __restrict__ xb, unsigned short* __restrict__ wout)
{
    int i = blockIdx.x * 256 + threadIdx.x;
    const float* src;
    unsigned short* dst;
    int j;
    if (i < 1048576) {
        src = x; dst = xb; j = i;
    } else {
        int k = i - 1048576;
        int m = k >> 18;
        src = (m == 0) ? w0 : (m == 1) ? w1 : (m == 2) ? w2 : w3;
        dst = wout + (size_t)m * 1048576;
        j = k & 262143;
    }
    float4 v = reinterpret_cast<const float4*>(src)[j];
    ushort4 o;
    o.x = f2bf(v.x); o.y = f2bf(v.y); o.z = f2bf(v.z); o.w = f2bf(v.w);
    reinterpret_cast<ushort4*>(dst)[j] = o;
}

// ---------------- fused QKV projection: BM=128 x BN=64 ----------------
// grid 1536 = 8 XCDs x (16m x 12n); each 64-col tile lies wholly in Q, K, or V.
// Q pre-scaled by 0.125*log2(e).
__global__ __launch_bounds__(256) void qkv_gemm(const unsigned short* __restrict__ X,
    const unsigned short* __restrict__ Wqkv,
    const float* __restrict__ bq, const float* __restrict__ bk, const float* __restrict__ bv,
    unsigned short* __restrict__ Qb, unsigned short* __restrict__ Kb, unsigned short* __restrict__ Vt)
{
    __shared__ __align__(16) unsigned short sA[128 * 64];   // 16 KB
    __shared__ __align__(16) unsigned short sW[64 * 64];    // 8 KB
    f32x4 acc[4][2] = {};
    const int id = blockIdx.x;
    const int xcd = id & 7, local = id >> 3;        // 1536 = 8 x 192
    const int m = (xcd & 1) * 16 + (local & 15);    // 2 m-chunks of 16
    const int n = (xcd >> 1) * 12 + (local >> 4);   // 4 n-chunks of 12
    const int m0 = m * 128, n0 = n * 64;

    const int tid  = threadIdx.x;
    const int lane = tid & 63;
    const int wv   = tid >> 6;
    const int wm   = wv >> 1, wn = wv & 1;   // 2x2 wave grid, 64x32 per wave
    const int lrow = lane >> 3;
    const int lchunk = (lane & 7) ^ lrow;

    char* sAc = reinterpret_cast<char*>(sA);
    char* sWc = reinterpret_cast<char*>(sW);

    for (int kt = 0; kt < 1024; kt += 64) {
        __syncthreads();
        #pragma unroll
        for (int j = 0; j < 4; ++j) {
            int row = (wv * 4 + j) * 8 + lrow;   // 0..127
            gload16(X + (size_t)(m0 + row) * 1024 + kt + lchunk * 8, sAc + (wv * 4 + j) * 1024);
        }
        #pragma unroll
        for (int j = 0; j < 2; ++j) {
            int row = (wv * 2 + j) * 8 + lrow;   // 0..63
            gload16(Wqkv + (size_t)(n0 + row) * 1024 + kt + lchunk * 8, sWc + (wv * 2 + j) * 1024);
        }
        __syncthreads();
        #pragma unroll
        for (int kk = 0; kk < 2; ++kk) {
            bf16x8 af[4], wf[2];
            #pragma unroll
            for (int r = 0; r < 4; ++r) {
                int rowA = wm * 64 + r * 16 + (lane & 15);
                int ca = ((kk * 4 + (lane >> 4)) ^ (rowA & 7)) * 16;
                af[r] = *reinterpret_cast<const bf16x8*>(sAc + rowA * 128 + ca);
            }
            #pragma unroll
            for (int c = 0; c < 2; ++c) {
                int rowW = wn * 32 + c * 16 + (lane & 15);
                int cw = ((kk * 4 + (lane >> 4)) ^ (rowW & 7)) * 16;
                wf[c] = *reinterpret_cast<const bf16x8*>(sWc + rowW * 128 + cw);
            }
            #pragma unroll
            for (int r = 0; r < 4; ++r)
                #pragma unroll
                for (int c = 0; c < 2; ++c)
                    acc[r][c] = __builtin_amdgcn_mfma_f32_16x16x32_bf16(af[r], wf[c], acc[r][c], 0, 0, 0);
        }
    }

    const int mid = n0 >> 10;                 // 0=Q 1=K 2=V
    const float* bias = (mid == 0) ? bq : (mid == 1) ? bk : bv;
    const float qs = (mid == 0) ? 0.18033688011112042f : 1.0f;   // 0.125*log2(e)
    #pragma unroll
    for (int r = 0; r < 4; ++r) {
        #pragma unroll
        for (int c = 0; c < 2; ++c) {
            int colg = n0 + wn * 32 + c * 16 + (lane & 15);
            int col = colg & 1023;
            float bb = bias[col];
            int row0 = m0 + wm * 64 + r * 16 + 4 * (lane >> 4);
            if (mid == 2) {
                ushort4 sv;
                sv.x = f2bf(acc[r][c][0] + bb);
                sv.y = f2bf(acc[r][c][1] + bb);
                sv.z = f2bf(acc[r][c][2] + bb);
                sv.w = f2bf(acc[r][c][3] + bb);
                *reinterpret_cast<ushort4*>(
                    Vt + ((size_t)((row0 >> 11) * 1024 + col)) * 2048 + (row0 & 2047)) = sv;
            } else {
                #pragma unroll
                for (int e = 0; e < 4; ++e) {
                    unsigned short bf = f2bf((acc[r][c][e] + bb) * qs);
                    if (mid == 0) Qb[(size_t)(row0 + e) * 1024 + col] = bf;
                    else          Kb[(size_t)(row0 + e) * 1024 + col] = bf;
                }
            }
        }
    }
}

// ---------------- output projection: BM=128 x BN=64 tiles, grid (32,16) ----------------
__global__ __launch_bounds__(256) void out_gemm(const unsigned short* __restrict__ O,
    const unsigned short* __restrict__ Wo, const float* __restrict__ bo,
    float* __restrict__ out)
{
    __shared__ __align__(16) unsigned short sA[128 * 64];   // 16 KB
    __shared__ __align__(16) unsigned short sW[64 * 64];    // 8 KB
    f32x4 acc[4][2] = {};
    const int m0 = blockIdx.x * 128, n0 = blockIdx.y * 64;

    const int tid  = threadIdx.x;
    const int lane = tid & 63;
    const int wv   = tid >> 6;
    const int wm   = wv >> 1, wn = wv & 1;   // 2x2 wave grid, 64x32 per wave
    const int lrow = lane >> 3;
    const int lchunk = (lane & 7) ^ lrow;

    char* sAc = reinterpret_cast<char*>(sA);
    char* sWc = reinterpret_cast<char*>(sW);

    for (int kt = 0; kt < 1024; kt += 64) {
        __syncthreads();
        #pragma unroll
        for (int j = 0; j < 4; ++j) {
            int row = (wv * 4 + j) * 8 + lrow;   // 0..127
            gload16(O + (size_t)(m0 + row) * 1024 + kt + lchunk * 8, sAc + (wv * 4 + j) * 1024);
        }
        #pragma unroll
        for (int j = 0; j < 2; ++j) {
            int row = (wv * 2 + j) * 8 + lrow;   // 0..63
            gload16(Wo + (size_t)(n0 + row) * 1024 + kt + lchunk * 8, sWc + (wv * 2 + j) * 1024);
        }
        __syncthreads();
        #pragma unroll
        for (int kk = 0; kk < 2; ++kk) {
            bf16x8 af[4], wf[2];
            #pragma unroll
            for (int r = 0; r < 4; ++r) {
                int rowA = wm * 64 + r * 16 + (lane & 15);
                int ca = ((kk * 4 + (lane >> 4)) ^ (rowA & 7)) * 16;
                af[r] = *reinterpret_cast<const bf16x8*>(sAc + rowA * 128 + ca);
            }
            #pragma unroll
            for (int c = 0; c < 2; ++c) {
                int rowW = wn * 32 + c * 16 + (lane & 15);
                int cw = ((kk * 4 + (lane >> 4)) ^ (rowW & 7)) * 16;
                wf[c] = *reinterpret_cast<const bf16x8*>(sWc + rowW * 128 + cw);
            }
            #pragma unroll
            for (int r = 0; r < 4; ++r)
                #pragma unroll
                for (int c = 0; c < 2; ++c)
                    acc[r][c] = __builtin_amdgcn_mfma_f32_16x16x32_bf16(af[r], wf[c], acc[r][c], 0, 0, 0);
        }
    }

    #pragma unroll
    for (int r = 0; r < 4; ++r) {
        #pragma unroll
        for (int c = 0; c < 2; ++c) {
            int col = n0 + wn * 32 + c * 16 + (lane & 15);
            float bb = bo[col];
            #pragma unroll
            for (int e = 0; e < 4; ++e) {
                int row = m0 + wm * 64 + r * 16 + 4 * (lane >> 4) + e;
                out[(size_t)row * 1024 + col] = acc[r][c][e] + bb;
            }
        }
    }
}

// ---------------- merge the two kv-halves (linear weights, shared zero shift) ----------------
__global__ __launch_bounds__(256) void combine_kernel(
    const unsigned short* __restrict__ O0, const unsigned short* __restrict__ O1,
    const float* __restrict__ lbase, unsigned short* __restrict__ Ob)
{
    int idx = blockIdx.x * 256 + threadIdx.x;
    int row = idx >> 7;              // 128 uint4 per row of 1024
    int h = (idx & 127) >> 3;        // 8 uint4 per head
    float lsum = lbase[row * 16 + h] + lbase[65536 + row * 16 + h];
    float inv = 1.0f / lsum;
    uint4 x0 = reinterpret_cast<const uint4*>(O0)[idx];
    uint4 x1 = reinterpret_cast<const uint4*>(O1)[idx];
    const unsigned* p0 = reinterpret_cast<const unsigned*>(&x0);
    const unsigned* p1 = reinterpret_cast<const unsigned*>(&x1);
    uint4 o;
    unsigned* po = reinterpret_cast<unsigned*>(&o);
    #pragma unroll
    for (int wd = 0; wd < 4; ++wd) {
        float lo = bf2f((unsigned short)(p0[wd] & 0xFFFF)) + bf2f((unsigned short)(p1[wd] & 0xFFFF));
        float hi = bf2f((unsigned short)(p0[wd] >> 16)) + bf2f((unsigned short)(p1[wd] >> 16));
        po[wd] = cvtpk_bf16(lo * inv, hi * inv);
    }
    reinterpret_cast<uint4*>(Ob)[idx] = o;
}

// ---------------- flash attention, kv-split x2, LDS-staged, 8-wave blocks ----------------
// grid 512 blocks of 512 threads, XCD-swizzled. Wave owns 32 Q rows (block = 256 q rows);
// 16 kv-tiles of 64 per half. p = exp2(S2) raw (shift-free); emits unnormalized U + linear l.
__global__ __launch_bounds__(512) void attn_kernel(const unsigned short* __restrict__ Qb,
    const unsigned short* __restrict__ Kb, const unsigned short* __restrict__ Vt,
    unsigned short* __restrict__ Oq0, unsigned short* __restrict__ Oq1,
    float* __restrict__ lbase)
{
    __shared__ __align__(16) unsigned short sK[2][64 * 64];   // [buf][kv][d]
    __shared__ __align__(16) unsigned short sV[2][64 * 64];   // [buf][d][kv]

    const int id = blockIdx.x;
    const int swz = (id & 7) * 64 + (id >> 3);          // bijective (512%8==0)
    const int qt = swz & 7;                             // 8 q-tiles of 256 rows
    const int bh = (swz >> 3) & 31;
    const int half = swz >> 8;                          // 0 or 1
    const int b = bh >> 4, h = bh & 15;
    const int tid = threadIdx.x, lane = tid & 63, wv = tid >> 6;   // wv 0..7
    const int qq = lane & 31, hi = lane >> 5;

    unsigned short* Oh = half ? Oq1 : Oq0;
    float* lq = lbase + half * 65536;

    const int qrow0 = b * 2048 + qt * 256 + wv * 32;
    const int kv0 = half * 1024;
    const int ntiles = 16;                   // 2048/2 kv rows / 64

    bf16x8 qf[4];
    #pragma unroll
    for (int ks = 0; ks < 4; ++ks)
        qf[ks] = *reinterpret_cast<const bf16x8*>(
            Qb + (size_t)(qrow0 + qq) * 1024 + h * 64 + ks * 16 + hi * 8);

    f32x16 oacc[2] = {};           // U^T: rows d, col q=qq (unnormalized)
    float l_sum = 0.f;

    const unsigned short* Kbase = Kb + (size_t)b * 2048 * 1024 + h * 64;
    const unsigned short* Vbase = Vt + (size_t)(bh * 64) * 2048;

    const int lrow = lane >> 3;              // 0..7
    const int lchunk = (lane & 7) ^ lrow;    // pre-swizzled source chunk

    char* sKbase = reinterpret_cast<char*>(sK);
    char* sVbase = reinterpret_cast<char*>(sV);

    // 8 waves x 8 rows = 64 rows; 1 gload16 per thread per matrix
    #define FILL(buf, kvoff)                                                              \
        {                                                                                 \
            int row = wv * 8 + lrow;                                                      \
            gload16(Kbase + (size_t)((kvoff) + row) * 1024 + lchunk * 8,                  \
                    sKbase + (buf) * 8192 + wv * 1024);                                   \
            gload16(Vbase + (size_t)row * 2048 + (kvoff) + lchunk * 8,                    \
                    sVbase + (buf) * 8192 + wv * 1024);                                   \
        }

    FILL(0, kv0)
    __syncthreads();

    for (int t = 0; t < ntiles; ++t) {
        const int cur = t & 1;
        if (t < ntiles - 1) { FILL(cur ^ 1, kv0 + (t + 1) * 64) }

        const char* bK = sKbase + cur * 8192;
        const char* bV = sVbase + cur * 8192;

        // S^T[kv][q] = K x Q (log2 domain)
        f32x16 pacc[2];
        __builtin_amdgcn_s_setprio(1);
        #pragma unroll
        for (int mt = 0; mt < 2; ++mt) {
            f32x16 acc = {};
            int row = mt * 32 + qq;
            #pragma unroll
            for (int ks = 0; ks < 4; ++ks) {
                int c = ((ks * 2 + hi) ^ (row & 7)) * 16;
                bf16x8 kf = *reinterpret_cast<const bf16x8*>(bK + row * 128 + c);
                acc = __builtin_amdgcn_mfma_f32_32x32x16_bf16(kf, qf[ks], acc, 0, 0, 0);
            }
            pacc[mt] = acc;
        }
        __builtin_amdgcn_s_setprio(0);

        // shift-free softmax: p = exp2(S2); 4 independent partial sums
        float rs0 = 0.f, rs1 = 0.f, rs2 = 0.f, rs3 = 0.f;
        #pragma unroll
        for (int mt = 0; mt < 2; ++mt) {
            #pragma unroll
            for (int r = 0; r < 16; r += 4) {
                float p0 = exp2_hw(pacc[mt][r + 0]);
                float p1 = exp2_hw(pacc[mt][r + 1]);
                float p2 = exp2_hw(pacc[mt][r + 2]);
                float p3 = exp2_hw(pacc[mt][r + 3]);
                pacc[mt][r + 0] = p0; rs0 += p0;
                pacc[mt][r + 1] = p1; rs1 += p1;
                pacc[mt][r + 2] = p2; rs2 += p2;
                pacc[mt][r + 3] = p3; rs3 += p3;
            }
        }
        l_sum += (rs0 + rs1) + (rs2 + rs3);

        // P^T -> bf16 B-fragments via cvt_pk + shfl_xor(32) half-exchange, then PV
        __builtin_amdgcn_s_setprio(1);
        #pragma unroll
        for (int mt = 0; mt < 2; ++mt) {
            #pragma unroll
            for (int halfk = 0; halfk < 2; ++halfk) {
                int r0 = halfk * 8;
                unsigned A0 = cvtpk_bf16(pacc[mt][r0 + 0], pacc[mt][r0 + 1]);
                unsigned A1 = cvtpk_bf16(pacc[mt][r0 + 2], pacc[mt][r0 + 3]);
                unsigned B0 = cvtpk_bf16(pacc[mt][r0 + 4], pacc[mt][r0 + 5]);
                unsigned B1 = cvtpk_bf16(pacc[mt][r0 + 6], pacc[mt][r0 + 7]);
                unsigned t0 = hi ? A0 : B0;
                unsigned t1 = hi ? A1 : B1;
                unsigned r0x = (unsigned)__shfl_xor((int)t0, 32);
                unsigned r1x = (unsigned)__shfl_xor((int)t1, 32);
                union { unsigned u[4]; bf16x8 v; } pf;
                pf.u[0] = hi ? r0x : A0;
                pf.u[1] = hi ? r1x : A1;
                pf.u[2] = hi ? B0 : r0x;
                pf.u[3] = hi ? B1 : r1x;
                int ks = mt * 2 + halfk;
                #pragma unroll
                for (int dt = 0; dt < 2; ++dt) {
                    int row = dt * 32 + qq;
                    int c = ((ks * 2 + hi) ^ (row & 7)) * 16;
                    bf16x8 vf = *reinterpret_cast<const bf16x8*>(bV + row * 128 + c);
                    oacc[dt] = __builtin_amdgcn_mfma_f32_32x32x16_bf16(vf, pf.v, oacc[dt], 0, 0, 0);
                }
            }
        }
        __builtin_amdgcn_s_setprio(0);
        __syncthreads();
    }

    // epilogue: store raw U (bf16) + half-total l (f32); normalization in combine
    #pragma unroll
    for (int dt = 0; dt < 2; ++dt) {
        #pragma unroll
        for (int rg = 0; rg < 4; ++rg) {
            int d0 = dt * 32 + rg * 8 + hi * 4;
            ushort4 stv;
            stv.x = f2bf(oacc[dt][rg * 4 + 0]);
            stv.y = f2bf(oacc[dt][rg * 4 + 1]);
            stv.z = f2bf(oacc[dt][rg * 4 + 2]);
            stv.w = f2bf(oacc[dt][rg * 4 + 3]);
            *reinterpret_cast<ushort4*>(Oh + (size_t)(qrow0 + qq) * 1024 + h * 64 + d0) = stv;
        }
    }
    l_sum = l_sum + __shfl_xor(l_sum, 32);
    if (hi == 0)
        lq[(qrow0 + qq) * 16 + h] = l_sum;
}

extern "C" void kernel_launch(void* const* d_in, const int* in_sizes, int n_in,
                              void* d_out, int out_size, void* d_ws, size_t ws_size,
                              hipStream_t stream)
{
    const float* x  = (const float*)d_in[0];
    const float* wq = (const float*)d_in[1];
    const float* bq = (const float*)d_in[2];
    const float* wk = (const float*)d_in[3];
    const float* bk = (const float*)d_in[4];
    const float* wv = (const float*)d_in[5];
    const float* bv = (const float*)d_in[6];
    const float* wo = (const float*)d_in[7];
    const float* bo = (const float*)d_in[8];
    float* out = (float*)d_out;

    char* ws = (char*)d_ws;
    const size_t MB = 1024 * 1024;
    unsigned short* xb   = (unsigned short*)(ws + 0);        // [4096,1024] bf16
    unsigned short* wqkv = (unsigned short*)(ws + 8 * MB);   // [3072,1024] bf16
    unsigned short* wob  = (unsigned short*)(ws + 14 * MB);  // [1024,1024] bf16
    unsigned short* Qb   = (unsigned short*)(ws + 16 * MB);  // [4096,1024] bf16 (→ Ob after attn)
    unsigned short* Kb   = (unsigned short*)(ws + 24 * MB);  // [4096,1024] bf16
    unsigned short* Vt   = (unsigned short*)(ws + 32 * MB);  // [2048,2048] bf16
    unsigned short* O0   = (unsigned short*)(ws + 40 * MB);  // [4096,1024] bf16 U-half 0
    unsigned short* O1   = (unsigned short*)(ws + 48 * MB);  // half 1
    float*          lse0 = (float*)(ws + 56 * MB);           // [2][4096,16] f32 linear l
    unsigned short* Ob   = Qb;                               // Qb dead after attn

    cvt_all<<<8192, 256, 0, stream>>>(x, wq, wk, wv, wo, xb, wqkv);   // xb + wqkv + wob

    qkv_gemm<<<1536, 256, 0, stream>>>(xb, wqkv, bq, bk, bv, Qb, Kb, Vt);
    attn_kernel<<<512, 512, 0, stream>>>(Qb, Kb, Vt, O0, O1, lse0);
    combine_kernel<<<2048, 256, 0, stream>>>(O0, O1, lse0, Ob);
    out_gemm<<<dim3(32, 16), 256, 0, stream>>>(Ob, wob, bo, out);
}